// Round 10
// baseline (125.309 us; speedup 1.0000x reference)
//
#include <hip/hip_runtime.h>

// NCC loss, fused z-sweep, v10 = R9 skeleton + sliding-window y-filter:
//  - yf computed by 64 threads (4 outs each, 9-window + 3 slides) into a
//    parity double-buffered yf[2]; owners consume yf(s-1) from the opposite
//    parity IN THE SAME PHASE -> still 2 barriers/slice (now unconditional).
//  - 29 fully-unrolled bodies: ring slot (CSLOT=(s-1)%9) and parity literal.
// Grid 1600 x 256, LDS ~22 KB, T14 reg-prefetch (R9) unchanged.

#define TX 16
#define TY 16
#define ZC 20
#define PH 24          // TY+8
#define PW 24          // TX+8
#define XFP 16         // float4 row stride
#define NSTEP 28       // ZC+8
#define NN 160
#define NPLANE (160*160)

__global__ void ncc_zero_ws(float* ws) { ws[0] = 0.0f; }

__global__ __launch_bounds__(256)
void ncc_fused(const float* __restrict__ pred, const float* __restrict__ target,
               float* __restrict__ ws) {
  __shared__ float2 st[PH * PW];        // staged (t,p)         4.6 KB
  __shared__ float4 xf4[PH * XFP];      // x-filt (t,p,t2,p2)   6.1 KB
  __shared__ float  xf1[PH * XFP];      // x-filt tp            1.5 KB
  __shared__ float4 yf4[2][TY * TX];    // xy-filt 4 moments    8.2 KB
  __shared__ float  yf1[2][TY * TX];    // xy-filt tp           2.0 KB
  __shared__ float  wsum[4];

  const int tid = threadIdx.x;
  const int tx = tid & 15;
  const int ty = tid >> 4;              // 0..15

  int b = blockIdx.x;
  const int xt = b % 10; b /= 10;
  const int yt = b % 10; b /= 10;
  const int zc = b % 8;  b /= 8;
  const int x0 = xt * TX, y0 = yt * TY, z0 = zc * ZC;
  const size_t bbase = (size_t)b * (size_t)NN * (size_t)NPLANE;

  // ---- hoisted z-invariant stage geometry (3 strided positions) ----
  int soff0, soff1, soff2;
  bool sv0, sv1, sv2;
  {
    const int yy = tid / PW, xx = tid - yy * PW;
    const int gy = y0 + yy - 4, gx = x0 + xx - 4;
    sv0 = ((unsigned)gy < NN) && ((unsigned)gx < NN);
    soff0 = gy * NN + gx;
  }
  {
    const int pos = tid + 256;
    const int yy = pos / PW, xx = pos - yy * PW;
    const int gy = y0 + yy - 4, gx = x0 + xx - 4;
    sv1 = ((unsigned)gy < NN) && ((unsigned)gx < NN);
    soff1 = gy * NN + gx;
  }
  {
    const int pos = tid + 512;
    const int yy = pos / PW, xx = pos - yy * PW;
    const int gy = y0 + yy - 4, gx = x0 + xx - 4;
    sv2 = (tid < 64) && ((unsigned)gy < NN) && ((unsigned)gx < NN);
    soff2 = gy * NN + gx;
  }

  float rt0, rp0, rt1, rp1, rt2, rp2;   // prefetch regs (named -> static)

#define PRELOAD(SS) do {                                                      \
    const int zi_ = z0 - 4 + (SS);                                            \
    if ((unsigned)zi_ < NN) {                                                 \
      const size_t zb_ = bbase + (size_t)zi_ * (size_t)NPLANE;                \
      rt0 = sv0 ? target[zb_ + soff0] : 0.0f;                                 \
      rp0 = sv0 ? pred[zb_ + soff0]   : 0.0f;                                 \
      rt1 = sv1 ? target[zb_ + soff1] : 0.0f;                                 \
      rp1 = sv1 ? pred[zb_ + soff1]   : 0.0f;                                 \
      rt2 = sv2 ? target[zb_ + soff2] : 0.0f;                                 \
      rp2 = sv2 ? pred[zb_ + soff2]   : 0.0f;                                 \
    }                                                                         \
  } while (0)

  // ---- 9-tap x-filter of one output (row YY, col XX) ----
#define XFOUT(YY, XX) do {                                                    \
    float s_t = 0, s_p = 0, s_t2 = 0, s_p2 = 0, s_tp = 0;                     \
    _Pragma("unroll")                                                         \
    for (int dx = 0; dx < 9; ++dx) {                                          \
      const float2 v = st[(YY) * PW + (XX) + dx];                             \
      s_t += v.x;                                                             \
      s_p += v.y;                                                             \
      s_t2 = fmaf(v.x, v.x, s_t2);                                            \
      s_p2 = fmaf(v.y, v.y, s_p2);                                            \
      s_tp = fmaf(v.x, v.y, s_tp);                                            \
    }                                                                         \
    xf4[(YY) * XFP + (XX)] = make_float4(s_t, s_p, s_t2, s_p2);               \
    xf1[(YY) * XFP + (XX)] = s_tp;                                            \
  } while (0)

  float buf0[9], buf1[9], buf2[9], buf3[9], buf4[9];
  float run0 = 0, run1 = 0, run2 = 0, run3 = 0, run4 = 0;
  #pragma unroll
  for (int j = 0; j < 9; ++j) { buf0[j]=0; buf1[j]=0; buf2[j]=0; buf3[j]=0; buf4[j]=0; }
  float acc = 0.0f;
  const float inv_kvol = 1.0f / 729.0f;

  // ---- body for slice S (produce) / slice S-1 (consume). S, CSLOT literal ----
#define ZBODY(S, CSLOT) do {                                                  \
    const int par_ = (S) & 1;                                                 \
    bool zv = false;                                                          \
    if ((S) < NSTEP) zv = ((unsigned)(z0 - 4 + (S)) < NN);   /* uniform */    \
    if ((S) < NSTEP && zv) {                                                  \
      st[tid]       = make_float2(rt0, rp0);                                  \
      st[tid + 256] = make_float2(rt1, rp1);                                  \
      if (tid < 64) st[tid + 512] = make_float2(rt2, rp2);                    \
    }                                                                         \
    __syncthreads();   /* A: st visible (always: guards yf(s-1) too) */       \
    if ((S) < NSTEP && zv) {                                                  \
      XFOUT(ty, tx);                              /* rows 0..15  */          \
      if (tid < 128) { XFOUT(16 + ty, tx); }      /* rows 16..23 */          \
    }                                                                         \
    __syncthreads();   /* B: xf visible; st reads done */                     \
    if ((S) + 1 < NSTEP) { PRELOAD((S) + 1); }                                \
    if ((S) < NSTEP && zv && tid < 64) {                                      \
      /* sliding yf: 4 outputs, rows r0..r0+3, col yx */                      \
      const int yx_ = tid & 15;                                               \
      const int r0_ = (tid >> 4) * 4;                                         \
      float w0 = 0, w1 = 0, w2 = 0, w3 = 0, w4 = 0;                           \
      _Pragma("unroll")                                                       \
      for (int k = 0; k < 9; ++k) {                                           \
        const float4 a = xf4[(r0_ + k) * XFP + yx_];                          \
        const float  c = xf1[(r0_ + k) * XFP + yx_];                          \
        w0 += a.x; w1 += a.y; w2 += a.z; w3 += a.w; w4 += c;                  \
      }                                                                       \
      yf4[par_][r0_ * TX + yx_] = make_float4(w0, w1, w2, w3);                \
      yf1[par_][r0_ * TX + yx_] = w4;                                         \
      _Pragma("unroll")                                                       \
      for (int k = 0; k < 3; ++k) {                                           \
        const float4 an = xf4[(r0_ + 9 + k) * XFP + yx_];                     \
        const float  cn = xf1[(r0_ + 9 + k) * XFP + yx_];                     \
        const float4 ao = xf4[(r0_ + k) * XFP + yx_];                         \
        const float  co = xf1[(r0_ + k) * XFP + yx_];                         \
        w0 += an.x - ao.x; w1 += an.y - ao.y;                                 \
        w2 += an.z - ao.z; w3 += an.w - ao.w; w4 += cn - co;                  \
        yf4[par_][(r0_ + 1 + k) * TX + yx_] = make_float4(w0, w1, w2, w3);    \
        yf1[par_][(r0_ + 1 + k) * TX + yx_] = w4;                             \
      }                                                                       \
    }                                                                         \
    if ((S) >= 1) {                                                           \
      /* consume slice S-1 from opposite parity (written 2 barriers ago) */   \
      const bool zvm1 = ((unsigned)(z0 - 4 + (S) - 1) < NN);                  \
      float cur0 = 0, cur1 = 0, cur2 = 0, cur3 = 0, cur4 = 0;                 \
      if (zvm1) {                                                             \
        const float4 a = yf4[par_ ^ 1][ty * TX + tx];                         \
        const float  c = yf1[par_ ^ 1][ty * TX + tx];                         \
        cur0 = a.x; cur1 = a.y; cur2 = a.z; cur3 = a.w; cur4 = c;             \
      }                                                                       \
      run0 += cur0 - buf0[(CSLOT)]; buf0[(CSLOT)] = cur0;                     \
      run1 += cur1 - buf1[(CSLOT)]; buf1[(CSLOT)] = cur1;                     \
      run2 += cur2 - buf2[(CSLOT)]; buf2[(CSLOT)] = cur2;                     \
      run3 += cur3 - buf3[(CSLOT)]; buf3[(CSLOT)] = cur3;                     \
      run4 += cur4 - buf4[(CSLOT)]; buf4[(CSLOT)] = cur4;                     \
      if ((S) - 1 >= 8) {                                                     \
        const float tavg = run0 * inv_kvol;                                   \
        const float pavg = run1 * inv_kvol;                                   \
        const float cross = run4 - pavg * run0;                               \
        const float tvar  = run2 - tavg * run0;                               \
        const float pvar  = run3 - pavg * run1;                               \
        acc += (cross * cross) / (tvar * pvar + 1e-5f);                       \
      }                                                                       \
    }                                                                         \
  } while (0)

  // ---- prologue: issue loads for slice 0 ----
  PRELOAD(0);

  // 29 bodies, fully unrolled; CSLOT = (S-1) % 9
  ZBODY(0, 0);  ZBODY(1, 0);  ZBODY(2, 1);  ZBODY(3, 2);  ZBODY(4, 3);
  ZBODY(5, 4);  ZBODY(6, 5);  ZBODY(7, 6);  ZBODY(8, 7);  ZBODY(9, 8);
  ZBODY(10, 0); ZBODY(11, 1); ZBODY(12, 2); ZBODY(13, 3); ZBODY(14, 4);
  ZBODY(15, 5); ZBODY(16, 6); ZBODY(17, 7); ZBODY(18, 8); ZBODY(19, 0);
  ZBODY(20, 1); ZBODY(21, 2); ZBODY(22, 3); ZBODY(23, 4); ZBODY(24, 5);
  ZBODY(25, 6); ZBODY(26, 7); ZBODY(27, 8); ZBODY(28, 0);
#undef ZBODY
#undef XFOUT
#undef PRELOAD

  // ---- reduction: wave shuffle -> LDS -> one atomicAdd per block ----
  #pragma unroll
  for (int off = 32; off > 0; off >>= 1)
    acc += __shfl_down(acc, off, 64);
  if ((tid & 63) == 0) wsum[tid >> 6] = acc;
  __syncthreads();
  if (tid == 0) {
    float tot = wsum[0] + wsum[1] + wsum[2] + wsum[3];
    atomicAdd(ws, tot);
  }
}

__global__ void ncc_finalize(const float* __restrict__ ws, float* __restrict__ out) {
  out[0] = -ws[0] * (1.0f / 8192000.0f);
}

extern "C" void kernel_launch(void* const* d_in, const int* in_sizes, int n_in,
                              void* d_out, int out_size, void* d_ws, size_t ws_size,
                              hipStream_t stream) {
  const float* pred   = (const float*)d_in[0];
  const float* target = (const float*)d_in[1];
  float* out = (float*)d_out;
  float* ws  = (float*)d_ws;

  ncc_zero_ws<<<1, 1, 0, stream>>>(ws);
  // grid: 10 x-tiles * 10 y-tiles * 8 z-chunks * 2 batches = 1600 blocks
  ncc_fused<<<1600, 256, 0, stream>>>(pred, target, ws);
  ncc_finalize<<<1, 1, 0, stream>>>(ws, out);
}

// Round 11
// 94.221 us; speedup vs baseline: 1.3299x; 1.3299x over previous
//
#include <hip/hip_runtime.h>

// NCC loss, fused z-sweep, v11 = R9 skeleton (loop-of-9, literal ring slots,
// T14 reg-prefetch, 2 barriers/slice) + sliding-window y-filter:
//   yf by 64 threads (4 outs each, 9-window + 3 slides) into parity
//   double-buffered yf[2]; owners consume yf(s-1) from opposite parity in
//   the same phase. Parity = LDS address only (runtime-safe); ring slot and
//   consume-slot are macro literals. Grid 1600 x 256, LDS ~22.6 KB.

#define TX 16
#define TY 16
#define ZC 20
#define PH 24          // TY+8
#define PW 24          // TX+8
#define XFP 16         // float4 row stride
#define NSTEP 28       // ZC+8
#define NN 160
#define NPLANE (160*160)

__global__ void ncc_zero_ws(float* ws) { ws[0] = 0.0f; }

__global__ __launch_bounds__(256)
void ncc_fused(const float* __restrict__ pred, const float* __restrict__ target,
               float* __restrict__ ws) {
  __shared__ float2 st[PH * PW];        // staged (t,p)         4.6 KB
  __shared__ float4 xf4[PH * XFP];      // x-filt (t,p,t2,p2)   6.1 KB
  __shared__ float  xf1[PH * XFP];      // x-filt tp            1.5 KB
  __shared__ float4 yf4[2][TY * TX];    // xy-filt 4 moments    8.2 KB
  __shared__ float  yf1[2][TY * TX];    // xy-filt tp           2.0 KB
  __shared__ float  wsum[4];

  const int tid = threadIdx.x;
  const int tx = tid & 15;
  const int ty = tid >> 4;              // 0..15

  int b = blockIdx.x;
  const int xt = b % 10; b /= 10;
  const int yt = b % 10; b /= 10;
  const int zc = b % 8;  b /= 8;
  const int x0 = xt * TX, y0 = yt * TY, z0 = zc * ZC;
  const size_t bbase = (size_t)b * (size_t)NN * (size_t)NPLANE;

  // ---- hoisted z-invariant stage geometry (3 strided positions) ----
  int soff0, soff1, soff2;
  bool sv0, sv1, sv2;
  {
    const int yy = tid / PW, xx = tid - yy * PW;
    const int gy = y0 + yy - 4, gx = x0 + xx - 4;
    sv0 = ((unsigned)gy < NN) && ((unsigned)gx < NN);
    soff0 = gy * NN + gx;
  }
  {
    const int pos = tid + 256;
    const int yy = pos / PW, xx = pos - yy * PW;
    const int gy = y0 + yy - 4, gx = x0 + xx - 4;
    sv1 = ((unsigned)gy < NN) && ((unsigned)gx < NN);
    soff1 = gy * NN + gx;
  }
  {
    const int pos = tid + 512;
    const int yy = pos / PW, xx = pos - yy * PW;
    const int gy = y0 + yy - 4, gx = x0 + xx - 4;
    sv2 = (tid < 64) && ((unsigned)gy < NN) && ((unsigned)gx < NN);
    soff2 = gy * NN + gx;
  }

  float rt0, rp0, rt1, rp1, rt2, rp2;   // prefetch regs (named -> static)

#define PRELOAD(SS) do {                                                      \
    const int zi_ = z0 - 4 + (SS);                                            \
    if ((unsigned)zi_ < NN) {                                                 \
      const size_t zb_ = bbase + (size_t)zi_ * (size_t)NPLANE;                \
      rt0 = sv0 ? target[zb_ + soff0] : 0.0f;                                 \
      rp0 = sv0 ? pred[zb_ + soff0]   : 0.0f;                                 \
      rt1 = sv1 ? target[zb_ + soff1] : 0.0f;                                 \
      rp1 = sv1 ? pred[zb_ + soff1]   : 0.0f;                                 \
      rt2 = sv2 ? target[zb_ + soff2] : 0.0f;                                 \
      rp2 = sv2 ? pred[zb_ + soff2]   : 0.0f;                                 \
    }                                                                         \
  } while (0)

  // ---- 9-tap x-filter of one output (row YY, col XX) ----
#define XFOUT(YY, XX) do {                                                    \
    float s_t = 0, s_p = 0, s_t2 = 0, s_p2 = 0, s_tp = 0;                     \
    _Pragma("unroll")                                                         \
    for (int dx = 0; dx < 9; ++dx) {                                          \
      const float2 v = st[(YY) * PW + (XX) + dx];                             \
      s_t += v.x;                                                             \
      s_p += v.y;                                                             \
      s_t2 = fmaf(v.x, v.x, s_t2);                                            \
      s_p2 = fmaf(v.y, v.y, s_p2);                                            \
      s_tp = fmaf(v.x, v.y, s_tp);                                            \
    }                                                                         \
    xf4[(YY) * XFP + (XX)] = make_float4(s_t, s_p, s_t2, s_p2);               \
    xf1[(YY) * XFP + (XX)] = s_tp;                                            \
  } while (0)

  float buf0[9], buf1[9], buf2[9], buf3[9], buf4[9];
  float run0 = 0, run1 = 0, run2 = 0, run3 = 0, run4 = 0;
  #pragma unroll
  for (int j = 0; j < 9; ++j) { buf0[j]=0; buf1[j]=0; buf2[j]=0; buf3[j]=0; buf4[j]=0; }
  float acc = 0.0f;
  const float inv_kvol = 1.0f / 729.0f;

  // ---- body: produce slice S, consume slice S-1. CSLOT = (S-1)%9 literal ----
#define ZBODY(S_EXPR, CSLOT) do {                                             \
    const int s_ = (S_EXPR);                                                  \
    const bool prod_ = (s_ < NSTEP) && ((unsigned)(z0 - 4 + s_) < NN);        \
    if (prod_) {                                                              \
      st[tid]       = make_float2(rt0, rp0);                                  \
      st[tid + 256] = make_float2(rt1, rp1);                                  \
      if (tid < 64) st[tid + 512] = make_float2(rt2, rp2);                    \
    }                                                                         \
    __syncthreads();   /* A: st visible */                                    \
    if (prod_) {                                                              \
      XFOUT(ty, tx);                              /* rows 0..15  */           \
      if (tid < 128) { XFOUT(16 + ty, tx); }      /* rows 16..23 */           \
    }                                                                         \
    __syncthreads();   /* B: xf visible; st reads done */                     \
    if (s_ + 1 < NSTEP) { PRELOAD(s_ + 1); }                                  \
    if (prod_ && tid < 64) {                                                  \
      /* sliding yf: 4 outputs, rows r0..r0+3, col yx -> yf[s&1] */           \
      float4* ya_ = yf4[s_ & 1];                                              \
      float*  yb_ = yf1[s_ & 1];                                              \
      const int yx_ = tid & 15;                                               \
      const int r0_ = (tid >> 4) * 4;                                         \
      float w0 = 0, w1 = 0, w2 = 0, w3 = 0, w4 = 0;                           \
      _Pragma("unroll")                                                       \
      for (int k = 0; k < 9; ++k) {                                           \
        const float4 a = xf4[(r0_ + k) * XFP + yx_];                          \
        const float  c = xf1[(r0_ + k) * XFP + yx_];                          \
        w0 += a.x; w1 += a.y; w2 += a.z; w3 += a.w; w4 += c;                  \
      }                                                                       \
      ya_[r0_ * TX + yx_] = make_float4(w0, w1, w2, w3);                      \
      yb_[r0_ * TX + yx_] = w4;                                               \
      _Pragma("unroll")                                                       \
      for (int k = 0; k < 3; ++k) {                                           \
        const float4 an = xf4[(r0_ + 9 + k) * XFP + yx_];                     \
        const float  cn = xf1[(r0_ + 9 + k) * XFP + yx_];                     \
        const float4 ao = xf4[(r0_ + k) * XFP + yx_];                         \
        const float  co = xf1[(r0_ + k) * XFP + yx_];                         \
        w0 += an.x - ao.x; w1 += an.y - ao.y;                                 \
        w2 += an.z - ao.z; w3 += an.w - ao.w; w4 += cn - co;                  \
        ya_[(r0_ + 1 + k) * TX + yx_] = make_float4(w0, w1, w2, w3);          \
        yb_[(r0_ + 1 + k) * TX + yx_] = w4;                                   \
      }                                                                       \
    }                                                                         \
    if (s_ >= 1) {                                                            \
      /* consume slice s-1 from opposite parity (2 barriers since write) */   \
      const bool zvm1_ = ((unsigned)(z0 - 4 + s_ - 1) < NN);                  \
      float cur0 = 0, cur1 = 0, cur2 = 0, cur3 = 0, cur4 = 0;                 \
      if (zvm1_) {                                                            \
        const float4 a = yf4[(s_ & 1) ^ 1][ty * TX + tx];                     \
        const float  c = yf1[(s_ & 1) ^ 1][ty * TX + tx];                     \
        cur0 = a.x; cur1 = a.y; cur2 = a.z; cur3 = a.w; cur4 = c;             \
      }                                                                       \
      run0 += cur0 - buf0[(CSLOT)]; buf0[(CSLOT)] = cur0;                     \
      run1 += cur1 - buf1[(CSLOT)]; buf1[(CSLOT)] = cur1;                     \
      run2 += cur2 - buf2[(CSLOT)]; buf2[(CSLOT)] = cur2;                     \
      run3 += cur3 - buf3[(CSLOT)]; buf3[(CSLOT)] = cur3;                     \
      run4 += cur4 - buf4[(CSLOT)]; buf4[(CSLOT)] = cur4;                     \
      if (s_ - 1 >= 8) {                                                      \
        const float tavg = run0 * inv_kvol;                                   \
        const float pavg = run1 * inv_kvol;                                   \
        const float cross = run4 - pavg * run0;                               \
        const float tvar  = run2 - tavg * run0;                               \
        const float pvar  = run3 - pavg * run1;                               \
        acc += (cross * cross) / (tvar * pvar + 1e-5f);                       \
      }                                                                       \
    }                                                                         \
  } while (0)

  // ---- prologue: issue loads for slice 0 ----
  PRELOAD(0);

  // bodies S=0..26 in loop-of-9 (one-slice live state); consume-slot=(S-1)%9
  for (int s0 = 0; s0 < 27; s0 += 9) {
    ZBODY(s0 + 0, 8); ZBODY(s0 + 1, 0); ZBODY(s0 + 2, 1);
    ZBODY(s0 + 3, 2); ZBODY(s0 + 4, 3); ZBODY(s0 + 5, 4);
    ZBODY(s0 + 6, 5); ZBODY(s0 + 7, 6); ZBODY(s0 + 8, 7);
  }
  // peeled tail: S=27 (produce 27, consume 26), S=28 (consume 27 only)
  ZBODY(27, 8);
  ZBODY(28, 0);
#undef ZBODY
#undef XFOUT
#undef PRELOAD

  // ---- reduction: wave shuffle -> LDS -> one atomicAdd per block ----
  #pragma unroll
  for (int off = 32; off > 0; off >>= 1)
    acc += __shfl_down(acc, off, 64);
  if ((tid & 63) == 0) wsum[tid >> 6] = acc;
  __syncthreads();
  if (tid == 0) {
    float tot = wsum[0] + wsum[1] + wsum[2] + wsum[3];
    atomicAdd(ws, tot);
  }
}

__global__ void ncc_finalize(const float* __restrict__ ws, float* __restrict__ out) {
  out[0] = -ws[0] * (1.0f / 8192000.0f);
}

extern "C" void kernel_launch(void* const* d_in, const int* in_sizes, int n_in,
                              void* d_out, int out_size, void* d_ws, size_t ws_size,
                              hipStream_t stream) {
  const float* pred   = (const float*)d_in[0];
  const float* target = (const float*)d_in[1];
  float* out = (float*)d_out;
  float* ws  = (float*)d_ws;

  ncc_zero_ws<<<1, 1, 0, stream>>>(ws);
  // grid: 10 x-tiles * 10 y-tiles * 8 z-chunks * 2 batches = 1600 blocks
  ncc_fused<<<1600, 256, 0, stream>>>(pred, target, ws);
  ncc_finalize<<<1, 1, 0, stream>>>(ws, out);
}